// Round 10
// baseline (52.514 us; speedup 1.0000x reference)
//
#include <hip/hip_runtime.h>
#include <hip/hip_fp16.h>
#include <hip/hip_fp8.h>
#include <stdint.h>

#define VOCAB 40000
#define NW    100
#define N1    100
#define N2    100
#define BB    4096
#define LL    343
#define PP    86      // pooling length: (343-1)/4 + 1
#define SROWB 104     // S row stride in BYTES: 40000*104 = 4.16 MB ~= one XCD L2

typedef _Float16 v8h __attribute__((ext_vector_type(8)));
typedef float    v4f __attribute__((ext_vector_type(4)));
typedef float    v2f __attribute__((ext_vector_type(2)));

union H8 { v8h v; _Float16 e[8]; };

__device__ __forceinline__ unsigned char enc_fp8(float v) {
#if __has_builtin(__builtin_amdgcn_cvt_pk_fp8_f32)
    int pk = __builtin_amdgcn_cvt_pk_fp8_f32(v, v, 0, false);
    return (unsigned char)(pk & 0xff);
#else
    __hip_fp8_e4m3 h(v);
    return h.__x;
#endif
}

__device__ __forceinline__ v2f dec2_fp8(unsigned int us) {
#if __has_builtin(__builtin_amdgcn_cvt_pk_f32_fp8)
    return __builtin_amdgcn_cvt_pk_f32_fp8((int)us, false);
#else
    __hip_fp8_e4m3 a, b;
    a.__x = (unsigned char)(us & 0xff);
    b.__x = (unsigned char)((us >> 8) & 0xff);
    v2f r; r.x = (float)a; r.y = (float)b; return r;
#endif
}

// ---------------------------------------------------------------------------
// k_table: blocks 0..624 compute S[v][f] = sum_k wv[v][k]*(W1[f][k]+W1[f][100+k])
// via mfma_f32_16x16x32_f16 (fp16 in, fp32 accum), output fp8 e4m3 at 104-B
// row stride (table fits one XCD L2). word_vec staged with nt loads (stream).
// Block 625: W2T[f][n] = W2[n][f].
// ---------------------------------------------------------------------------
__global__ __launch_bounds__(256) void k_table(const float* __restrict__ word_vec,
                                               const float* __restrict__ W1,
                                               const float* __restrict__ W2,
                                               unsigned char* __restrict__ S8,
                                               float* __restrict__ W2T) {
    const int tid = threadIdx.x;

    if (blockIdx.x == 625) {            // W2T[f][n] = W2[n][f]
        for (int idx = tid; idx < N1 * N2; idx += 256) {
            int f = idx / N2;
            int n = idx - f * N2;
            W2T[idx] = W2[n * N1 + f];
        }
        return;
    }

    __shared__ _Float16 wt[64 * 128];    // word tile, swizzled   (16 KB)
    __shared__ _Float16 eff[112 * 128];  // eff filters, swizzled (28 KB)
    const int vbase = blockIdx.x * 64;

    // ---- stage word tile: 64 rows x 16 chunks of 8 halfs (nt stream reads) ----
    for (int c = tid; c < 64 * 16; c += 256) {
        const int r = c >> 4, cc = c & 15;
        H8 u;
        const float* src = word_vec + (size_t)(vbase + r) * NW + cc * 8;
        if (cc < 12) {
            const v4f x0 = __builtin_nontemporal_load(reinterpret_cast<const v4f*>(src));
            const v4f x1 = __builtin_nontemporal_load(reinterpret_cast<const v4f*>(src + 4));
            u.e[0] = (_Float16)x0.x; u.e[1] = (_Float16)x0.y;
            u.e[2] = (_Float16)x0.z; u.e[3] = (_Float16)x0.w;
            u.e[4] = (_Float16)x1.x; u.e[5] = (_Float16)x1.y;
            u.e[6] = (_Float16)x1.z; u.e[7] = (_Float16)x1.w;
        } else {
#pragma unroll
            for (int j = 0; j < 8; ++j) {
                const int k = cc * 8 + j;
                u.e[j] = (k < NW) ? (_Float16)word_vec[(size_t)(vbase + r) * NW + k]
                                  : (_Float16)0.f;
            }
        }
        *reinterpret_cast<v8h*>(&wt[r * 128 + ((cc ^ (r & 7)) << 3)]) = u.v;
    }
    // ---- stage eff: 112 rows x 16 chunks (W1 reused across blocks: normal loads) ----
    for (int c = tid; c < 112 * 16; c += 256) {
        const int f = c >> 4, cc = c & 15;
        H8 u;
        if (f < N1 && cc < 12) {
            const float4 a0 = *reinterpret_cast<const float4*>(&W1[f * 200 + cc * 8]);
            const float4 a1 = *reinterpret_cast<const float4*>(&W1[f * 200 + cc * 8 + 4]);
            const float4 b0 = *reinterpret_cast<const float4*>(&W1[f * 200 + 100 + cc * 8]);
            const float4 b1 = *reinterpret_cast<const float4*>(&W1[f * 200 + 104 + cc * 8]);
            u.e[0] = (_Float16)(a0.x + b0.x); u.e[1] = (_Float16)(a0.y + b0.y);
            u.e[2] = (_Float16)(a0.z + b0.z); u.e[3] = (_Float16)(a0.w + b0.w);
            u.e[4] = (_Float16)(a1.x + b1.x); u.e[5] = (_Float16)(a1.y + b1.y);
            u.e[6] = (_Float16)(a1.z + b1.z); u.e[7] = (_Float16)(a1.w + b1.w);
        } else {
#pragma unroll
            for (int j = 0; j < 8; ++j) {
                const int k = cc * 8 + j;
                u.e[j] = (f < N1 && k < NW)
                    ? (_Float16)(W1[f * 200 + k] + W1[f * 200 + 100 + k])
                    : (_Float16)0.f;
            }
        }
        *reinterpret_cast<v8h*>(&eff[f * 128 + ((cc ^ (f & 7)) << 3)]) = u.v;
    }
    __syncthreads();

    const int lane = tid & 63;
    const int wave = tid >> 6;
    const int rbase = wave * 16;
    const int mr = lane & 15;
    const int kg = lane >> 4;

    v8h a[4];
#pragma unroll
    for (int s = 0; s < 4; ++s) {
        const int k = s * 32 + kg * 8;
        a[s] = *reinterpret_cast<const v8h*>(
            &wt[(rbase + mr) * 128 + (k ^ ((mr & 7) << 3))]);
    }

#pragma unroll
    for (int t = 0; t < 7; ++t) {
        v4f acc = {0.f, 0.f, 0.f, 0.f};
        const int f = t * 16 + mr;
#pragma unroll
        for (int s = 0; s < 4; ++s) {
            const int k = s * 32 + kg * 8;
            const v8h b = *reinterpret_cast<const v8h*>(
                &eff[f * 128 + (k ^ ((f & 7) << 3))]);
            acc = __builtin_amdgcn_mfma_f32_16x16x32_f16(a[s], b, acc, 0, 0, 0);
        }
        if (f < N1) {
            const size_t vrow = (size_t)(vbase + rbase + kg * 4);
#pragma unroll
            for (int j = 0; j < 4; ++j)
                S8[(vrow + j) * SROWB + f] = enc_fp8(acc[j]);
        }
    }
}

// ---------------------------------------------------------------------------
// k_main: one block (256 thr = 4 waves) per batch row. Waves split the 86
// windows {22,22,22,20+tail}; 4 windows (16 loads) in flight. Table rows at
// 104-B stride (L2-resident). ent_words nt-loaded; out nt-stored.
// Epilogue: 4 waves x 25 lanes read W2T rows as float4.
// ---------------------------------------------------------------------------
__global__ __launch_bounds__(256) void k_main(const int* __restrict__ ent_words,
                                              const unsigned char* __restrict__ S8,
                                              const float* __restrict__ W2T,
                                              float* __restrict__ out) {
    __shared__ __align__(16) int woff[344];
    __shared__ __align__(16) float part[4][N1];
    __shared__ __align__(16) float hsum[N1];

    const int b    = blockIdx.x;
    const int tid  = threadIdx.x;
    const int lane = tid & 63;
    const int wave = tid >> 6;

    for (int l = tid; l < LL; l += 256) {
        const int id = __builtin_nontemporal_load(&ent_words[b * LL + l]);
        woff[l] = id * SROWB;                     // byte offset (104-B rows)
    }
    __syncthreads();

    const char* Sc = reinterpret_cast<const char*>(S8);
    const uint32_t laneoff = (uint32_t)lane * 2u;

    if (lane < 50) {
        float acc0 = 0.f, acc1 = 0.f;
        const int pbeg = wave * 22;
        const int pfull_end = (wave == 3) ? 85 : pbeg + 22;   // full windows only
        int p = pbeg;
        // ---- 4 windows per iteration: 16 loads in flight ----
        for (; p + 3 < pfull_end; p += 4) {
            const int4 wa = *reinterpret_cast<const int4*>(&woff[p * 4]);
            const int4 wb = *reinterpret_cast<const int4*>(&woff[p * 4 + 4]);
            const int4 wc = *reinterpret_cast<const int4*>(&woff[p * 4 + 8]);
            const int4 wd = *reinterpret_cast<const int4*>(&woff[p * 4 + 12]);
            const unsigned short sa0 = *reinterpret_cast<const unsigned short*>(Sc + ((uint32_t)wa.x + laneoff));
            const unsigned short sa1 = *reinterpret_cast<const unsigned short*>(Sc + ((uint32_t)wa.y + laneoff));
            const unsigned short sa2 = *reinterpret_cast<const unsigned short*>(Sc + ((uint32_t)wa.z + laneoff));
            const unsigned short sa3 = *reinterpret_cast<const unsigned short*>(Sc + ((uint32_t)wa.w + laneoff));
            const unsigned short sb0 = *reinterpret_cast<const unsigned short*>(Sc + ((uint32_t)wb.x + laneoff));
            const unsigned short sb1 = *reinterpret_cast<const unsigned short*>(Sc + ((uint32_t)wb.y + laneoff));
            const unsigned short sb2 = *reinterpret_cast<const unsigned short*>(Sc + ((uint32_t)wb.z + laneoff));
            const unsigned short sb3 = *reinterpret_cast<const unsigned short*>(Sc + ((uint32_t)wb.w + laneoff));
            const unsigned short sc0 = *reinterpret_cast<const unsigned short*>(Sc + ((uint32_t)wc.x + laneoff));
            const unsigned short sc1 = *reinterpret_cast<const unsigned short*>(Sc + ((uint32_t)wc.y + laneoff));
            const unsigned short sc2 = *reinterpret_cast<const unsigned short*>(Sc + ((uint32_t)wc.z + laneoff));
            const unsigned short sc3 = *reinterpret_cast<const unsigned short*>(Sc + ((uint32_t)wc.w + laneoff));
            const unsigned short sd0 = *reinterpret_cast<const unsigned short*>(Sc + ((uint32_t)wd.x + laneoff));
            const unsigned short sd1 = *reinterpret_cast<const unsigned short*>(Sc + ((uint32_t)wd.y + laneoff));
            const unsigned short sd2 = *reinterpret_cast<const unsigned short*>(Sc + ((uint32_t)wd.z + laneoff));
            const unsigned short sd3 = *reinterpret_cast<const unsigned short*>(Sc + ((uint32_t)wd.w + laneoff));
            const v2f ra0 = dec2_fp8(sa0), ra1 = dec2_fp8(sa1), ra2 = dec2_fp8(sa2), ra3 = dec2_fp8(sa3);
            const v2f rb0 = dec2_fp8(sb0), rb1 = dec2_fp8(sb1), rb2 = dec2_fp8(sb2), rb3 = dec2_fp8(sb3);
            const v2f rc0 = dec2_fp8(sc0), rc1 = dec2_fp8(sc1), rc2 = dec2_fp8(sc2), rc3 = dec2_fp8(sc3);
            const v2f rd0 = dec2_fp8(sd0), rd1 = dec2_fp8(sd1), rd2 = dec2_fp8(sd2), rd3 = dec2_fp8(sd3);
            acc0 += fmaxf(fmaxf(fmaxf(ra0.x, ra1.x), fmaxf(ra2.x, ra3.x)), 0.f)
                  + fmaxf(fmaxf(fmaxf(rb0.x, rb1.x), fmaxf(rb2.x, rb3.x)), 0.f)
                  + fmaxf(fmaxf(fmaxf(rc0.x, rc1.x), fmaxf(rc2.x, rc3.x)), 0.f)
                  + fmaxf(fmaxf(fmaxf(rd0.x, rd1.x), fmaxf(rd2.x, rd3.x)), 0.f);
            acc1 += fmaxf(fmaxf(fmaxf(ra0.y, ra1.y), fmaxf(ra2.y, ra3.y)), 0.f)
                  + fmaxf(fmaxf(fmaxf(rb0.y, rb1.y), fmaxf(rb2.y, rb3.y)), 0.f)
                  + fmaxf(fmaxf(fmaxf(rc0.y, rc1.y), fmaxf(rc2.y, rc3.y)), 0.f)
                  + fmaxf(fmaxf(fmaxf(rd0.y, rd1.y), fmaxf(rd2.y, rd3.y)), 0.f);
        }
        // ---- pair remainder ----
        for (; p + 1 < pfull_end; p += 2) {
            const int4 wa = *reinterpret_cast<const int4*>(&woff[p * 4]);
            const int4 wb = *reinterpret_cast<const int4*>(&woff[p * 4 + 4]);
            const unsigned short sa0 = *reinterpret_cast<const unsigned short*>(Sc + ((uint32_t)wa.x + laneoff));
            const unsigned short sa1 = *reinterpret_cast<const unsigned short*>(Sc + ((uint32_t)wa.y + laneoff));
            const unsigned short sa2 = *reinterpret_cast<const unsigned short*>(Sc + ((uint32_t)wa.z + laneoff));
            const unsigned short sa3 = *reinterpret_cast<const unsigned short*>(Sc + ((uint32_t)wa.w + laneoff));
            const unsigned short sb0 = *reinterpret_cast<const unsigned short*>(Sc + ((uint32_t)wb.x + laneoff));
            const unsigned short sb1 = *reinterpret_cast<const unsigned short*>(Sc + ((uint32_t)wb.y + laneoff));
            const unsigned short sb2 = *reinterpret_cast<const unsigned short*>(Sc + ((uint32_t)wb.z + laneoff));
            const unsigned short sb3 = *reinterpret_cast<const unsigned short*>(Sc + ((uint32_t)wb.w + laneoff));
            const v2f ra0 = dec2_fp8(sa0), ra1 = dec2_fp8(sa1), ra2 = dec2_fp8(sa2), ra3 = dec2_fp8(sa3);
            const v2f rb0 = dec2_fp8(sb0), rb1 = dec2_fp8(sb1), rb2 = dec2_fp8(sb2), rb3 = dec2_fp8(sb3);
            acc0 += fmaxf(fmaxf(fmaxf(ra0.x, ra1.x), fmaxf(ra2.x, ra3.x)), 0.f)
                  + fmaxf(fmaxf(fmaxf(rb0.x, rb1.x), fmaxf(rb2.x, rb3.x)), 0.f);
            acc1 += fmaxf(fmaxf(fmaxf(ra0.y, ra1.y), fmaxf(ra2.y, ra3.y)), 0.f)
                  + fmaxf(fmaxf(fmaxf(rb0.y, rb1.y), fmaxf(rb2.y, rb3.y)), 0.f);
        }
        if (p < pfull_end) {   // single leftover full window
            const int4 wa = *reinterpret_cast<const int4*>(&woff[p * 4]);
            const unsigned short s0 = *reinterpret_cast<const unsigned short*>(Sc + ((uint32_t)wa.x + laneoff));
            const unsigned short s1 = *reinterpret_cast<const unsigned short*>(Sc + ((uint32_t)wa.y + laneoff));
            const unsigned short s2 = *reinterpret_cast<const unsigned short*>(Sc + ((uint32_t)wa.z + laneoff));
            const unsigned short s3 = *reinterpret_cast<const unsigned short*>(Sc + ((uint32_t)wa.w + laneoff));
            const v2f r0 = dec2_fp8(s0), r1 = dec2_fp8(s1), r2 = dec2_fp8(s2), r3 = dec2_fp8(s3);
            acc0 += fmaxf(fmaxf(fmaxf(r0.x, r1.x), fmaxf(r2.x, r3.x)), 0.f);
            acc1 += fmaxf(fmaxf(fmaxf(r0.y, r1.y), fmaxf(r2.y, r3.y)), 0.f);
        }
        if (wave == 3) {       // tail window 85: tokens 340..342
            const unsigned short s0 = *reinterpret_cast<const unsigned short*>(Sc + ((uint32_t)woff[340] + laneoff));
            const unsigned short s1 = *reinterpret_cast<const unsigned short*>(Sc + ((uint32_t)woff[341] + laneoff));
            const unsigned short s2 = *reinterpret_cast<const unsigned short*>(Sc + ((uint32_t)woff[342] + laneoff));
            const v2f r0 = dec2_fp8(s0), r1 = dec2_fp8(s1), r2 = dec2_fp8(s2);
            acc0 += fmaxf(fmaxf(fmaxf(r0.x, r1.x), r2.x), 0.f);
            acc1 += fmaxf(fmaxf(fmaxf(r0.y, r1.y), r2.y), 0.f);
        }
        part[wave][2 * lane]     = acc0;
        part[wave][2 * lane + 1] = acc1;
    }
    __syncthreads();

    if (tid < N1) {
        hsum[tid] = part[0][tid] + part[1][tid] + part[2][tid] + part[3][tid];
    }
    __syncthreads();

    // ---- epilogue: wave w covers f in [25w, 25w+25); lanes 0..24 hold n-quads
    if (lane < 25) {
        v4f o4 = {0.f, 0.f, 0.f, 0.f};
        const int fbeg = wave * 25;
#pragma unroll 5
        for (int f = fbeg; f < fbeg + 25; ++f) {
            const float s = hsum[f];
            const float4 wq = *reinterpret_cast<const float4*>(&W2T[f * N2 + 4 * lane]);
            o4.x += s * wq.x; o4.y += s * wq.y; o4.z += s * wq.z; o4.w += s * wq.w;
        }
        *reinterpret_cast<v4f*>(&part[wave][4 * lane]) = o4;   // reuse part as partials
    }
    __syncthreads();

    if (tid < N2) {
        const float o = (part[0][tid] + part[1][tid] + part[2][tid] + part[3][tid])
                        * (1.0f / (float)PP);
        __builtin_nontemporal_store(o, &out[b * N2 + tid]);
    }
}

// ---------------------------------------------------------------------------
extern "C" void kernel_launch(void* const* d_in, const int* in_sizes, int n_in,
                              void* d_out, int out_size, void* d_ws, size_t ws_size,
                              hipStream_t stream) {
    const int*   ent_words = (const int*)d_in[0];
    const float* word_vec  = (const float*)d_in[1];
    const float* W1        = (const float*)d_in[2];
    const float* W2        = (const float*)d_in[3];
    float* out = (float*)d_out;

    unsigned char* S8  = (unsigned char*)d_ws;                          // 4.16 MB
    float*         W2T = (float*)((char*)d_ws + (size_t)VOCAB * SROWB);

    k_table<<<626, 256, 0, stream>>>(word_vec, W1, W2, S8, W2T);
    k_main<<<BB, 256, 0, stream>>>(ent_words, S8, W2T, out);
}

// Round 11
// 48.039 us; speedup vs baseline: 1.0931x; 1.0931x over previous
//
#include <hip/hip_runtime.h>
#include <hip/hip_fp16.h>
#include <hip/hip_fp8.h>
#include <stdint.h>

#define VOCAB 40000
#define NW    100
#define N1    100
#define N2    100
#define BB    4096
#define LL    343
#define PP    86      // pooling length: (343-1)/4 + 1
#define SROWB 128     // S row stride in BYTES (one 128-B cache line, fp8)

typedef _Float16 v8h __attribute__((ext_vector_type(8)));
typedef float    v4f __attribute__((ext_vector_type(4)));
typedef float    v2f __attribute__((ext_vector_type(2)));

union H8 { v8h v; _Float16 e[8]; };

__device__ __forceinline__ unsigned char enc_fp8(float v) {
#if __has_builtin(__builtin_amdgcn_cvt_pk_fp8_f32)
    int pk = __builtin_amdgcn_cvt_pk_fp8_f32(v, v, 0, false);
    return (unsigned char)(pk & 0xff);
#else
    __hip_fp8_e4m3 h(v);
    return h.__x;
#endif
}

__device__ __forceinline__ v2f dec2_fp8(unsigned int us) {
#if __has_builtin(__builtin_amdgcn_cvt_pk_f32_fp8)
    return __builtin_amdgcn_cvt_pk_f32_fp8((int)us, false);
#else
    __hip_fp8_e4m3 a, b;
    a.__x = (unsigned char)(us & 0xff);
    b.__x = (unsigned char)((us >> 8) & 0xff);
    v2f r; r.x = (float)a; r.y = (float)b; return r;
#endif
}

// ---------------------------------------------------------------------------
// k_table: blocks 0..624 compute S[v][f] = sum_k wv[v][k]*(W1[f][k]+W1[f][100+k])
// via mfma_f32_16x16x32_f16 (fp16 in, fp32 accum), output fp8 e4m3 rows of
// 128 B. 64 vocab rows/block, 4 waves, 7 col-tiles x 4 k-steps. LDS
// XOR-swizzled for conflict-free ds_read_b128. Block 625: W2 transpose.
// (Identical to the round-7 version — best measured config.)
// ---------------------------------------------------------------------------
__global__ __launch_bounds__(256) void k_table(const float* __restrict__ word_vec,
                                               const float* __restrict__ W1,
                                               const float* __restrict__ W2,
                                               unsigned char* __restrict__ S8,
                                               float* __restrict__ W2T) {
    const int tid = threadIdx.x;

    if (blockIdx.x == 625) {            // W2T[f][n] = W2[n][f]
        for (int idx = tid; idx < N1 * N2; idx += 256) {
            int f = idx / N2;
            int n = idx - f * N2;
            W2T[idx] = W2[n * N1 + f];
        }
        return;
    }

    __shared__ _Float16 wt[64 * 128];    // word tile, swizzled   (16 KB)
    __shared__ _Float16 eff[112 * 128];  // eff filters, swizzled (28 KB)
    const int vbase = blockIdx.x * 64;

    // ---- stage word tile: 64 rows x 16 chunks of 8 halfs ----
    for (int c = tid; c < 64 * 16; c += 256) {
        const int r = c >> 4, cc = c & 15;
        H8 u;
        const float* src = word_vec + (size_t)(vbase + r) * NW + cc * 8;
        if (cc < 12) {
            const float4 x0 = *reinterpret_cast<const float4*>(src);
            const float4 x1 = *reinterpret_cast<const float4*>(src + 4);
            u.e[0] = (_Float16)x0.x; u.e[1] = (_Float16)x0.y;
            u.e[2] = (_Float16)x0.z; u.e[3] = (_Float16)x0.w;
            u.e[4] = (_Float16)x1.x; u.e[5] = (_Float16)x1.y;
            u.e[6] = (_Float16)x1.z; u.e[7] = (_Float16)x1.w;
        } else {
#pragma unroll
            for (int j = 0; j < 8; ++j) {
                const int k = cc * 8 + j;
                u.e[j] = (k < NW) ? (_Float16)word_vec[(size_t)(vbase + r) * NW + k]
                                  : (_Float16)0.f;
            }
        }
        *reinterpret_cast<v8h*>(&wt[r * 128 + ((cc ^ (r & 7)) << 3)]) = u.v;
    }
    // ---- stage eff: 112 rows x 16 chunks ----
    for (int c = tid; c < 112 * 16; c += 256) {
        const int f = c >> 4, cc = c & 15;
        H8 u;
        if (f < N1 && cc < 12) {
            const float4 a0 = *reinterpret_cast<const float4*>(&W1[f * 200 + cc * 8]);
            const float4 a1 = *reinterpret_cast<const float4*>(&W1[f * 200 + cc * 8 + 4]);
            const float4 b0 = *reinterpret_cast<const float4*>(&W1[f * 200 + 100 + cc * 8]);
            const float4 b1 = *reinterpret_cast<const float4*>(&W1[f * 200 + 104 + cc * 8]);
            u.e[0] = (_Float16)(a0.x + b0.x); u.e[1] = (_Float16)(a0.y + b0.y);
            u.e[2] = (_Float16)(a0.z + b0.z); u.e[3] = (_Float16)(a0.w + b0.w);
            u.e[4] = (_Float16)(a1.x + b1.x); u.e[5] = (_Float16)(a1.y + b1.y);
            u.e[6] = (_Float16)(a1.z + b1.z); u.e[7] = (_Float16)(a1.w + b1.w);
        } else {
#pragma unroll
            for (int j = 0; j < 8; ++j) {
                const int k = cc * 8 + j;
                u.e[j] = (f < N1 && k < NW)
                    ? (_Float16)(W1[f * 200 + k] + W1[f * 200 + 100 + k])
                    : (_Float16)0.f;
            }
        }
        *reinterpret_cast<v8h*>(&eff[f * 128 + ((cc ^ (f & 7)) << 3)]) = u.v;
    }
    __syncthreads();

    const int lane = tid & 63;
    const int wave = tid >> 6;
    const int rbase = wave * 16;
    const int mr = lane & 15;
    const int kg = lane >> 4;

    v8h a[4];
#pragma unroll
    for (int s = 0; s < 4; ++s) {
        const int k = s * 32 + kg * 8;
        a[s] = *reinterpret_cast<const v8h*>(
            &wt[(rbase + mr) * 128 + (k ^ ((mr & 7) << 3))]);
    }

#pragma unroll
    for (int t = 0; t < 7; ++t) {
        v4f acc = {0.f, 0.f, 0.f, 0.f};
        const int f = t * 16 + mr;
#pragma unroll
        for (int s = 0; s < 4; ++s) {
            const int k = s * 32 + kg * 8;
            const v8h b = *reinterpret_cast<const v8h*>(
                &eff[f * 128 + (k ^ ((f & 7) << 3))]);
            acc = __builtin_amdgcn_mfma_f32_16x16x32_f16(a[s], b, acc, 0, 0, 0);
        }
        if (f < N1) {
            const size_t vrow = (size_t)(vbase + rbase + kg * 4);
#pragma unroll
            for (int j = 0; j < 4; ++j)
                S8[(vrow + j) * SROWB + f] = enc_fp8(acc[j]);
        }
    }
}

// ---------------------------------------------------------------------------
// k_main: block = 128 thr = 2 waves; EACH WAVE OWNS ONE BATCH ROW end-to-end
// (woff staging + all 86 windows + hsum write) with NO block barriers in the
// gather — waves are fully decoupled so one wave's L2-miss latency never
// stalls the other. One __syncthreads, then a block-cooperative epilogue:
// threads 0..99 own output column n and REUSE each W2T[f][n] read across
// both rows (100 coalesced dword loads amortized over 2 rows).
// ---------------------------------------------------------------------------
__global__ __launch_bounds__(128) void k_main(const int* __restrict__ ent_words,
                                              const unsigned char* __restrict__ S8,
                                              const float* __restrict__ W2T,
                                              float* __restrict__ out) {
    __shared__ __align__(16) int   woff[2][344];
    __shared__ __align__(16) float hsum[2][104];

    const int tid  = threadIdx.x;
    const int lane = tid & 63;
    const int wave = tid >> 6;
    const int b    = blockIdx.x * 2 + wave;       // this wave's row

    // ---- per-wave woff staging (wave-local LDS; no barrier needed) ----
    for (int l = lane; l < LL; l += 64)
        woff[wave][l] = ent_words[b * LL + l] << 7;   // byte offset (128-B rows)

    const char* Sc = reinterpret_cast<const char*>(S8);
    const uint32_t laneoff = (uint32_t)lane * 2u;
    const int* wf = woff[wave];

    if (lane < 50) {
        float acc0 = 0.f, acc1 = 0.f;
        int p = 0;
        // ---- 4 windows per iteration: 16 loads in flight ----
        for (; p + 3 < 85; p += 4) {
            const int4 wa = *reinterpret_cast<const int4*>(&wf[p * 4]);
            const int4 wb = *reinterpret_cast<const int4*>(&wf[p * 4 + 4]);
            const int4 wc = *reinterpret_cast<const int4*>(&wf[p * 4 + 8]);
            const int4 wd = *reinterpret_cast<const int4*>(&wf[p * 4 + 12]);
            const unsigned short sa0 = *reinterpret_cast<const unsigned short*>(Sc + ((uint32_t)wa.x + laneoff));
            const unsigned short sa1 = *reinterpret_cast<const unsigned short*>(Sc + ((uint32_t)wa.y + laneoff));
            const unsigned short sa2 = *reinterpret_cast<const unsigned short*>(Sc + ((uint32_t)wa.z + laneoff));
            const unsigned short sa3 = *reinterpret_cast<const unsigned short*>(Sc + ((uint32_t)wa.w + laneoff));
            const unsigned short sb0 = *reinterpret_cast<const unsigned short*>(Sc + ((uint32_t)wb.x + laneoff));
            const unsigned short sb1 = *reinterpret_cast<const unsigned short*>(Sc + ((uint32_t)wb.y + laneoff));
            const unsigned short sb2 = *reinterpret_cast<const unsigned short*>(Sc + ((uint32_t)wb.z + laneoff));
            const unsigned short sb3 = *reinterpret_cast<const unsigned short*>(Sc + ((uint32_t)wb.w + laneoff));
            const unsigned short sc0 = *reinterpret_cast<const unsigned short*>(Sc + ((uint32_t)wc.x + laneoff));
            const unsigned short sc1 = *reinterpret_cast<const unsigned short*>(Sc + ((uint32_t)wc.y + laneoff));
            const unsigned short sc2 = *reinterpret_cast<const unsigned short*>(Sc + ((uint32_t)wc.z + laneoff));
            const unsigned short sc3 = *reinterpret_cast<const unsigned short*>(Sc + ((uint32_t)wc.w + laneoff));
            const unsigned short sd0 = *reinterpret_cast<const unsigned short*>(Sc + ((uint32_t)wd.x + laneoff));
            const unsigned short sd1 = *reinterpret_cast<const unsigned short*>(Sc + ((uint32_t)wd.y + laneoff));
            const unsigned short sd2 = *reinterpret_cast<const unsigned short*>(Sc + ((uint32_t)wd.z + laneoff));
            const unsigned short sd3 = *reinterpret_cast<const unsigned short*>(Sc + ((uint32_t)wd.w + laneoff));
            const v2f ra0 = dec2_fp8(sa0), ra1 = dec2_fp8(sa1), ra2 = dec2_fp8(sa2), ra3 = dec2_fp8(sa3);
            const v2f rb0 = dec2_fp8(sb0), rb1 = dec2_fp8(sb1), rb2 = dec2_fp8(sb2), rb3 = dec2_fp8(sb3);
            const v2f rc0 = dec2_fp8(sc0), rc1 = dec2_fp8(sc1), rc2 = dec2_fp8(sc2), rc3 = dec2_fp8(sc3);
            const v2f rd0 = dec2_fp8(sd0), rd1 = dec2_fp8(sd1), rd2 = dec2_fp8(sd2), rd3 = dec2_fp8(sd3);
            acc0 += fmaxf(fmaxf(fmaxf(ra0.x, ra1.x), fmaxf(ra2.x, ra3.x)), 0.f)
                  + fmaxf(fmaxf(fmaxf(rb0.x, rb1.x), fmaxf(rb2.x, rb3.x)), 0.f)
                  + fmaxf(fmaxf(fmaxf(rc0.x, rc1.x), fmaxf(rc2.x, rc3.x)), 0.f)
                  + fmaxf(fmaxf(fmaxf(rd0.x, rd1.x), fmaxf(rd2.x, rd3.x)), 0.f);
            acc1 += fmaxf(fmaxf(fmaxf(ra0.y, ra1.y), fmaxf(ra2.y, ra3.y)), 0.f)
                  + fmaxf(fmaxf(fmaxf(rb0.y, rb1.y), fmaxf(rb2.y, rb3.y)), 0.f)
                  + fmaxf(fmaxf(fmaxf(rc0.y, rc1.y), fmaxf(rc2.y, rc3.y)), 0.f)
                  + fmaxf(fmaxf(fmaxf(rd0.y, rd1.y), fmaxf(rd2.y, rd3.y)), 0.f);
        }
        {   // leftover full window p=84
            const int4 wa = *reinterpret_cast<const int4*>(&wf[84 * 4]);
            const unsigned short s0 = *reinterpret_cast<const unsigned short*>(Sc + ((uint32_t)wa.x + laneoff));
            const unsigned short s1 = *reinterpret_cast<const unsigned short*>(Sc + ((uint32_t)wa.y + laneoff));
            const unsigned short s2 = *reinterpret_cast<const unsigned short*>(Sc + ((uint32_t)wa.z + laneoff));
            const unsigned short s3 = *reinterpret_cast<const unsigned short*>(Sc + ((uint32_t)wa.w + laneoff));
            const v2f r0 = dec2_fp8(s0), r1 = dec2_fp8(s1), r2 = dec2_fp8(s2), r3 = dec2_fp8(s3);
            acc0 += fmaxf(fmaxf(fmaxf(r0.x, r1.x), fmaxf(r2.x, r3.x)), 0.f);
            acc1 += fmaxf(fmaxf(fmaxf(r0.y, r1.y), fmaxf(r2.y, r3.y)), 0.f);
        }
        {   // tail window 85: tokens 340..342
            const unsigned short s0 = *reinterpret_cast<const unsigned short*>(Sc + ((uint32_t)wf[340] + laneoff));
            const unsigned short s1 = *reinterpret_cast<const unsigned short*>(Sc + ((uint32_t)wf[341] + laneoff));
            const unsigned short s2 = *reinterpret_cast<const unsigned short*>(Sc + ((uint32_t)wf[342] + laneoff));
            const v2f r0 = dec2_fp8(s0), r1 = dec2_fp8(s1), r2 = dec2_fp8(s2);
            acc0 += fmaxf(fmaxf(fmaxf(r0.x, r1.x), r2.x), 0.f);
            acc1 += fmaxf(fmaxf(fmaxf(r0.y, r1.y), r2.y), 0.f);
        }
        hsum[wave][2 * lane]     = acc0;
        hsum[wave][2 * lane + 1] = acc1;
    }
    __syncthreads();   // the ONLY block barrier

    // ---- cooperative epilogue: thread n computes out for BOTH rows,
    //      reusing each W2T[f][n] load across the 2 rows ----
    if (tid < N2) {
        const int n = tid;
        float o0 = 0.f, o1 = 0.f;
#pragma unroll 4
        for (int f = 0; f < N1; ++f) {
            const float w2 = W2T[f * N2 + n];     // coalesced across threads 0..99
            o0 += hsum[0][f] * w2;                // LDS broadcast
            o1 += hsum[1][f] * w2;
        }
        const float inv = 1.0f / (float)PP;
        out[(size_t)(blockIdx.x * 2 + 0) * N2 + n] = o0 * inv;
        out[(size_t)(blockIdx.x * 2 + 1) * N2 + n] = o1 * inv;
    }
}

// ---------------------------------------------------------------------------
extern "C" void kernel_launch(void* const* d_in, const int* in_sizes, int n_in,
                              void* d_out, int out_size, void* d_ws, size_t ws_size,
                              hipStream_t stream) {
    const int*   ent_words = (const int*)d_in[0];
    const float* word_vec  = (const float*)d_in[1];
    const float* W1        = (const float*)d_in[2];
    const float* W2        = (const float*)d_in[3];
    float* out = (float*)d_out;

    unsigned char* S8  = (unsigned char*)d_ws;                          // 5.12 MB
    float*         W2T = (float*)((char*)d_ws + (size_t)VOCAB * SROWB);

    k_table<<<626, 256, 0, stream>>>(word_vec, W1, W2, S8, W2T);
    k_main<<<BB / 2, 128, 0, stream>>>(ent_words, S8, W2T, out);
}